// Round 10
// baseline (60.568 us; speedup 1.0000x reference)
//
#include <hip/hip_runtime.h>
#include <math.h>

#define NUM_H 256
#define NP    64        // poles per h
#define LL    8192      // sequence length
#define NHALF 4096      // LL/2 (complex FFT size)
#define NTA   256       // threads, Cauchy kernel
#define NTB   1024      // threads, FFT kernel
#define NFLD  18        // v2f fields per pole-pair in the const table

typedef float v2f __attribute__((ext_vector_type(2)));

// v_sin_f32 / v_cos_f32 take input in REVOLUTIONS (D = sin(S0 * 2pi)).

// Constant-table field order, per (h, pole-pair k), all v2f {even,odd}:
//  0 nwisq = -wi^2            1 c4  = wz/2 + wi^2
//  2 c2    = 2*wz             3 c3  = 2*(wi^2+wz)
//  4 wi                       5 wz  = wr^2
//  6 nwz   = -wz              7 w2i = 2*wi
//  8 wx    = -wr              9..16 v00r,v00i,v01r,v01i,v10r,v10i,v11r,v11i
// 17 pad
// (wr = Re(w)*dt, wi = Im(w)*dt;  dd = g^2 + c2*(y^2 + c4) == d1*d2)

// ------------- Prep kernel: build per-(h,pair) SGPR-constant table ----------
__global__ void prep_consts(const float* __restrict__ w_ri,
                            const float* __restrict__ p_ri,
                            const float* __restrict__ q_ri,
                            const float* __restrict__ B_ri,
                            const float* __restrict__ C_ri,
                            const float* __restrict__ log_dt,
                            v2f* __restrict__ tab)
{
    const int h = blockIdx.x;
    const int k = threadIdx.x;          // pole pair 0..31
    const float dt = expf(log_dt[h]);
    float out[2 * NFLD];
    #pragma unroll
    for (int o = 0; o < 2; ++o) {
        const int n = 2 * k + o;
        const float2 w = ((const float2*)w_ri)[h * NP + n];
        const float2 p = ((const float2*)p_ri)[h * NP + n];
        const float2 q = ((const float2*)q_ri)[h * NP + n];
        const float2 B = ((const float2*)B_ri)[h * NP + n];
        const float2 C = ((const float2*)C_ri)[h * NP + n];
        const float wr = w.x * dt, wi = w.y * dt;
        const float wz = wr * wr, wisq = wi * wi;
        out[0 * 2 + o]  = -wisq;
        out[1 * 2 + o]  = 0.5f * wz + wisq;      // c4
        out[2 * 2 + o]  = 2.f * wz;              // c2
        out[3 * 2 + o]  = 2.f * (wisq + wz);     // c3
        out[4 * 2 + o]  = wi;
        out[5 * 2 + o]  = wz;
        out[6 * 2 + o]  = -wz;                   // nwz
        out[7 * 2 + o]  = 2.f * wi;              // w2i
        out[8 * 2 + o]  = -wr;                   // wx
        out[9 * 2 + o]  = B.x * C.x + B.y * C.y; // v00r
        out[10 * 2 + o] = B.y * C.x - B.x * C.y; // v00i
        out[11 * 2 + o] = p.x * C.x + p.y * C.y; // v01r
        out[12 * 2 + o] = p.y * C.x - p.x * C.y; // v01i
        out[13 * 2 + o] = B.x * q.x + B.y * q.y; // v10r
        out[14 * 2 + o] = B.y * q.x - B.x * q.y; // v10i
        out[15 * 2 + o] = p.x * q.x + p.y * q.y; // v11r
        out[16 * 2 + o] = p.y * q.x - p.x * q.y; // v11i
        out[17 * 2 + o] = 0.f;
    }
    v2f* dst = tab + ((size_t)h * 32 + k) * NFLD;
    #pragma unroll
    for (int i = 0; i < NFLD; ++i) dst[i] = (v2f){out[2 * i], out[2 * i + 1]};
}

// ---------------- Kernel A: Cauchy sum + Woodbury -> spectrum ----------------
// Each lane owns ONE bin; pole-pair per iteration via modifier-free VOP3P
// packed-f32 asm. ALL per-pair constants are wave-uniform -> scalar loads ->
// "s" asm operands (free SGPR read per VALU op); zero LDS, zero DS reads.
// Every packed instruction reads at most ONE SGPR pair.
__global__ __launch_bounds__(NTA, 6)
void cauchy_phase(const v2f* __restrict__ tab,
                  const float* __restrict__ log_dt,
                  float*       __restrict__ spec,   // (H, 4096) float2 rows (= d_out)
                  float2*      __restrict__ nyq)    // (H,) Nyquist bins (= d_ws)
{
    const int h     = blockIdx.y;
    const int chunk = blockIdx.x;      // 16 chunks of 256 bins
    const int tid   = threadIdx.x;
    const float dt  = expf(log_dt[h]);
    const v2f* pc   = tab + (size_t)h * 32 * NFLD;

    const int l = (chunk << 8) + tid;       // 0..4095
    // y = Im(z) = 2*tan(pi*l/L); rev = l/16384 (exact dyadic)
    const float rev = (float)l * 6.103515625e-5f;
    const float sn  = __builtin_amdgcn_sinf(rev);
    const float cn  = fmaxf(__builtin_amdgcn_cosf(rev), 4.3711388e-8f);
    const float y   = 2.0f * sn * __builtin_amdgcn_rcpf(cn);
    const float ysq = y * y;
    const v2f yA   = {ysq, ysq};                 // y^2
    const v2f yA2  = {2.f * ysq, 2.f * ysq};     // 2*y^2
    const v2f y4s  = {4.f * y, 4.f * y};         // 4*y
    const v2f ny2s = {-2.f * y, -2.f * y};       // -2*y

    v2f a0 = 0.f, a1 = 0.f, a2 = 0.f, a3 = 0.f;
    v2f a4 = 0.f, a5 = 0.f, a6 = 0.f, a7 = 0.f;
    #pragma unroll 1
    for (int k = 0; k < 32; ++k) {
        const v2f* f = pc + k * NFLD;
        const v2f nwisq = f[0], c4 = f[1], c2 = f[2], c3 = f[3];
        const v2f wi2 = f[4], wz2 = f[5], nwz2 = f[6], w2i = f[7], wx2 = f[8];
        const v2f v00r2 = f[9],  v00i2 = f[10], v01r2 = f[11], v01i2 = f[12];
        const v2f v10r2 = f[13], v10i2 = f[14], v11r2 = f[15], v11i2 = f[16];

        v2f g, t, gg, dd;
        asm("v_pk_add_f32 %0, %4, %5\n\t"        // g  = y^2 + (-wi^2)
            "v_pk_add_f32 %1, %4, %6\n\t"        // t  = y^2 + c4
            "v_pk_mul_f32 %2, %0, %0\n\t"        // gg = g*g
            "v_pk_fma_f32 %3, %7, %1, %2"        // dd = c2*t + gg
            : "=&v"(g), "=&v"(t), "=&v"(gg), "=&v"(dd)
            : "v"(yA), "s"(nwisq), "s"(c4), "s"(c2));

        const v2f ir = {__builtin_amdgcn_rcpf(dd.x), __builtin_amdgcn_rcpf(dd.y)};

        v2f Sr, Di, SiN, Dr, irx;
        asm("v_pk_add_f32 %0, %5, %6\n\t"        // SI  = 2y^2 + c3      (d1+d2)
            "v_pk_mul_f32 %1, %7, %8\n\t"        // DI  = 4y * wi        (d2-d1)
            "v_pk_add_f32 %2, %9, %10\n\t"       // h1  = g + wz
            "v_pk_add_f32 %3, %9, %11\n\t"       // h2  = g + (-wz)
            "v_pk_mul_f32 %2, %12, %2\n\t"       // SPn = -2y * h1       (-(u1+u2))
            "v_pk_mul_f32 %3, %13, %3\n\t"       // SM  = 2wi * h2       ((u1-u2))
            "v_pk_mul_f32 %4, %14, %15\n\t"      // irx = wx * ir
            "v_pk_mul_f32 %0, %0, %4\n\t"        // Sr  = SI * irx
            "v_pk_mul_f32 %1, %1, %4\n\t"        // Di  = DI * irx
            "v_pk_mul_f32 %3, %3, %15\n\t"       // Dr  = SM * ir
            "v_pk_mul_f32 %2, %2, %15"           // SiN = SPn * ir       (= Si)
            : "=&v"(Sr), "=&v"(Di), "=&v"(SiN), "=&v"(Dr), "=&v"(irx)
            : "v"(yA2), "s"(c3), "v"(y4s), "s"(wi2), "v"(g), "s"(wz2),
              "s"(nwz2), "v"(ny2s), "s"(w2i), "s"(wx2), "v"(ir));

        asm("v_pk_fma_f32 %0, %12, %8, %0\n\t"   // a0 += v00r*Sr
            "v_pk_fma_f32 %0, %13, %10, %0\n\t"  // a0 += v00i*Dr
            "v_pk_fma_f32 %1, %12, %9, %1\n\t"   // a1 += v00r*SiN
            "v_pk_fma_f32 %1, %13, %11, %1\n\t"  // a1 += v00i*Di
            "v_pk_fma_f32 %2, %14, %8, %2\n\t"
            "v_pk_fma_f32 %2, %15, %10, %2\n\t"
            "v_pk_fma_f32 %3, %14, %9, %3\n\t"
            "v_pk_fma_f32 %3, %15, %11, %3\n\t"
            "v_pk_fma_f32 %4, %16, %8, %4\n\t"
            "v_pk_fma_f32 %4, %17, %10, %4\n\t"
            "v_pk_fma_f32 %5, %16, %9, %5\n\t"
            "v_pk_fma_f32 %5, %17, %11, %5\n\t"
            "v_pk_fma_f32 %6, %18, %8, %6\n\t"
            "v_pk_fma_f32 %6, %19, %10, %6\n\t"
            "v_pk_fma_f32 %7, %18, %9, %7\n\t"
            "v_pk_fma_f32 %7, %19, %11, %7"
            : "+v"(a0), "+v"(a1), "+v"(a2), "+v"(a3),
              "+v"(a4), "+v"(a5), "+v"(a6), "+v"(a7)
            : "v"(Sr), "v"(SiN), "v"(Dr), "v"(Di),
              "s"(v00r2), "s"(v00i2), "s"(v01r2), "s"(v01i2),
              "s"(v10r2), "s"(v10i2), "s"(v11r2), "s"(v11i2));
    }

    // horizontal add over the pole-pair halves, then Woodbury
    {
        const float a00r = (a0.x + a0.y) * dt, a00i = (a1.x + a1.y) * dt;
        const float a01r = (a2.x + a2.y) * dt, a01i = (a3.x + a3.y) * dt;
        const float a10r = (a4.x + a4.y) * dt, a10i = (a5.x + a5.y) * dt;
        const float a11r = (a6.x + a6.y) * dt, a11i = (a7.x + a7.y) * dt;
        const float numr = a01r * a10r - a01i * a10i;
        const float numi = a01r * a10i + a01i * a10r;
        const float dwr = 1.f + a11r, dwi = a11i;
        const float idw = __builtin_amdgcn_rcpf(dwr * dwr + dwi * dwi);
        const float qr = (numr * dwr + numi * dwi) * idw;
        const float qi = (numi * dwr - numr * dwi) * idw;
        const float kfr = a00r - qr, kfi = a00i - qi;
        const float fi  = 0.5f * y;        // 2/(1+nodes) = 1 + i*tan(pi*l/L)
        float2* grow = (float2*)(spec + (size_t)h * LL);
        grow[l] = make_float2(kfr - kfi * fi, kfi + kfr * fi);
    }

    // ---- Nyquist bin l=4096: one pole per lane of wave 0 of chunk 15 ----
    if (chunk == 15 && tid < 64) {
        const int n = tid;
        const int k = n >> 1, o = n & 1;
        const v2f* fz = pc + k * NFLD;
        const float wi = o ? fz[4].y : fz[4].x;
        const float wz = o ? fz[5].y : fz[5].x;
        const float wx = o ? fz[8].y : fz[8].x;
        const float v00r = o ? fz[9].y  : fz[9].x,  v00i = o ? fz[10].y : fz[10].x;
        const float v01r = o ? fz[11].y : fz[11].x, v01i = o ? fz[12].y : fz[12].x;
        const float v10r = o ? fz[13].y : fz[13].x, v10i = o ? fz[14].y : fz[14].x;
        const float v11r = o ? fz[15].y : fz[15].x, v11i = o ? fz[16].y : fz[16].x;
        // rev = 0.25 -> cos = 0 exactly; clamp reproduces reference's f32 z ~ 4.58e7
        const float y4 = 2.0f * __builtin_amdgcn_rcpf(4.3711388e-8f);
        const float t1 = y4 - wi, t2 = y4 + wi;
        const float i1 = __builtin_amdgcn_rcpf(fmaf(t1, t1, wz));
        const float i2 = __builtin_amdgcn_rcpf(fmaf(t2, t2, wz));
        const float u1 = t1 * i1, u2 = t2 * i2;
        const float Sr = wx * (i1 + i2);
        const float Si = -(u1 + u2);
        const float Dr = u1 - u2;
        const float Di = wx * (i1 - i2);
        float e0 = v00r * Sr + v00i * Dr, e1 = v00r * Si + v00i * Di;
        float e2 = v01r * Sr + v01i * Dr, e3 = v01r * Si + v01i * Di;
        float e4 = v10r * Sr + v10i * Dr, e5 = v10r * Si + v10i * Di;
        float e6 = v11r * Sr + v11i * Dr, e7 = v11r * Si + v11i * Di;
        #pragma unroll
        for (int m = 1; m < 64; m <<= 1) {
            e0 += __shfl_xor(e0, m);  e1 += __shfl_xor(e1, m);
            e2 += __shfl_xor(e2, m);  e3 += __shfl_xor(e3, m);
            e4 += __shfl_xor(e4, m);  e5 += __shfl_xor(e5, m);
            e6 += __shfl_xor(e6, m);  e7 += __shfl_xor(e7, m);
        }
        if (tid == 0) {
            const float a00r = e0 * dt, a00i = e1 * dt;
            const float a01r = e2 * dt, a01i = e3 * dt;
            const float a10r = e4 * dt, a10i = e5 * dt;
            const float a11r = e6 * dt, a11i = e7 * dt;
            const float numr = a01r * a10r - a01i * a10i;
            const float numi = a01r * a10i + a01i * a10r;
            const float dwr = 1.f + a11r, dwi = a11i;
            const float idw = __builtin_amdgcn_rcpf(dwr * dwr + dwi * dwi);
            const float qr = (numr * dwr + numi * dwi) * idw;
            const float qi = (numi * dwr - numr * dwi) * idw;
            const float kfr = a00r - qr, kfi = a00i - qi;
            const float fi  = 0.5f * y4;
            nyq[h] = make_float2(kfr - kfi * fi, kfi + kfr * fi);
        }
    }
}

// ---------------- Kernel B: pack + radix-4 Stockham iFFT + store -------------
__global__ __launch_bounds__(NTB)
void ifft_phase(float* __restrict__ io, const float2* __restrict__ nyq)
{
    __shared__ float2 sA[NHALF];
    __shared__ float2 sB[NHALF];

    const int h   = blockIdx.x;
    const int tid = threadIdx.x;
    float2* grow = (float2*)(io + (size_t)h * LL);

    // pack irfft(L) into complex iFFT(L/2), natural order:
    // Z[k] = (1/L)[(G[k]+conj(G[N-k])) + i*e^{+2pi i k/L}(G[k]-conj(G[N-k]))]
    #pragma unroll
    for (int ki = 0; ki < 4; ++ki) {
        const int k = tid + NTB * ki;
        const float2 Gk = grow[k];
        const float2 Gn = (k == 0) ? nyq[h] : grow[NHALF - k];
        const float Ar = Gk.x + Gn.x, Ai = Gk.y - Gn.y;
        const float Br = Gk.x - Gn.x, Bi = Gk.y + Gn.y;
        const float rev = (float)k * 1.220703125e-4f;   // k/8192
        const float cw = __builtin_amdgcn_cosf(rev);
        const float sw = __builtin_amdgcn_sinf(rev);
        const float sc = 1.0f / (float)LL;
        sA[k] = make_float2((Ar - cw * Bi - sw * Br) * sc,
                            (Ai + cw * Br - sw * Bi) * sc);
    }
    __syncthreads();

    // 6 radix-4 Stockham stages (inverse FFT, e^{+i} twiddles), ping-pong sA<->sB
    float2* pin  = sA;
    float2* pout = sB;
    #pragma unroll
    for (int s = 0; s < 6; ++s) {
        const int ls2 = 2 * s;
        const int Ls  = 1 << ls2;
        const int j   = tid;
        const int k   = j & (Ls - 1);
        const int tb  = k << (10 - ls2);
        const float fr = (float)tb * 2.44140625e-4f;    // tb/4096 revolutions
        const float c1 = __builtin_amdgcn_cosf(fr);
        const float s1 = __builtin_amdgcn_sinf(fr);
        const float c2 = __builtin_amdgcn_cosf(2.0f * fr);
        const float s2 = __builtin_amdgcn_sinf(2.0f * fr);
        const float c3 = __builtin_amdgcn_cosf(3.0f * fr);
        const float s3 = __builtin_amdgcn_sinf(3.0f * fr);
        float2 u0 = pin[j];
        float2 u1 = pin[j + 1024];
        float2 u2 = pin[j + 2048];
        float2 u3 = pin[j + 3072];
        float a, b;
        a = u1.x * c1 - u1.y * s1;  b = u1.x * s1 + u1.y * c1;  u1 = make_float2(a, b);
        a = u2.x * c2 - u2.y * s2;  b = u2.x * s2 + u2.y * c2;  u2 = make_float2(a, b);
        a = u3.x * c3 - u3.y * s3;  b = u3.x * s3 + u3.y * c3;  u3 = make_float2(a, b);
        const float t0r = u0.x + u2.x, t0i = u0.y + u2.y;
        const float t1r = u0.x - u2.x, t1i = u0.y - u2.y;
        const float t2r = u1.x + u3.x, t2i = u1.y + u3.y;
        const float t3r = u3.y - u1.y, t3i = u1.x - u3.x;   // i*(u1-u3)
        const int ob = ((j - k) << 2) + k;
        pout[ob]          = make_float2(t0r + t2r, t0i + t2i);
        pout[ob + Ls]     = make_float2(t1r + t3r, t1i + t3i);
        pout[ob + 2 * Ls] = make_float2(t0r - t2r, t0i - t2i);
        pout[ob + 3 * Ls] = make_float2(t1r - t3r, t1i - t3i);
        float2* tmp = pin; pin = pout; pout = tmp;
        __syncthreads();
    }

    // final data lands in sA; x[2j]=Re, x[2j+1]=Im -> coalesced float2 store
    #pragma unroll
    for (int ji = 0; ji < 4; ++ji) {
        const int j = tid + NTB * ji;
        grow[j] = sA[j];
    }
}

extern "C" void kernel_launch(void* const* d_in, const int* in_sizes, int n_in,
                              void* d_out, int out_size, void* d_ws, size_t ws_size,
                              hipStream_t stream) {
    const float* w   = (const float*)d_in[0];
    const float* p   = (const float*)d_in[1];
    const float* q   = (const float*)d_in[2];
    const float* B   = (const float*)d_in[3];
    const float* C   = (const float*)d_in[4];
    const float* ldt = (const float*)d_in[5];
    float*  spec = (float*)d_out;                       // spectrum staged in d_out
    float2* nyq  = (float2*)d_ws;                       // 256 * 8 B Nyquist bins
    v2f*    tab  = (v2f*)((char*)d_ws + 4096);          // 1.15 MB constant table

    prep_consts<<<NUM_H, 32, 0, stream>>>(w, p, q, B, C, ldt, tab);
    dim3 gridA(16, NUM_H);
    cauchy_phase<<<gridA, NTA, 0, stream>>>(tab, ldt, spec, nyq);
    ifft_phase<<<NUM_H, NTB, 0, stream>>>(spec, nyq);
}

// Round 12
// 57.656 us; speedup vs baseline: 1.0505x; 1.0505x over previous
//
#include <hip/hip_runtime.h>
#include <math.h>

#define NUM_H 256
#define NP    64        // poles per h
#define LL    8192      // sequence length
#define NHALF 4096      // LL/2 (complex FFT size)
#define NTA   256       // threads, Cauchy kernel
#define NTB   1024      // threads, FFT kernel

typedef float v2f __attribute__((ext_vector_type(2)));

// v_sin_f32 / v_cos_f32 take input in REVOLUTIONS (D = sin(S0 * 2pi)).

// Per pole-pair constants; every field is a native v2f pair so the LDS load
// lands directly in an even-aligned VGPR pair = direct VOP3P asm operand.
struct PolePair {
    v2f nwisq, c1;     // floats 0-3   nwisq = -wi^2 ; c1 = wz^2 + 2*wz*wi^2
    v2f c2,    c3;     // 4-7          c2 = 2*wz     ; c3 = 2*(wi^2+wz)
    v2f wi,    wz;     // 8-11
    v2f nwz,   w2i;    // 12-15        nwz = -wz     ; w2i = 2*wi
    v2f wx,    pad;    // 16-19        wx = -wr
    v2f v00r,  v00i;   // 20-23        B*conj(C)
    v2f v01r,  v01i;   // 24-27        p*conj(C)
    v2f v10r,  v10i;   // 28-31        B*conj(q)
    v2f v11r,  v11i;   // 32-35        p*conj(q)
};

// ---------------- Kernel A: Cauchy sum + Woodbury -> spectrum ----------------
// Each lane owns ONE bin; inner loop processes a pole PAIR per iteration with
// modifier-free VOP3P packed-f32 asm (proven correct in rounds 7/9).
// min-waves/EU = 8: VGPR use is 36, so occupancy was capped only by the old
// launch-bounds hint (round 9: 52% occupancy, VALUBusy 63%).
//
// Identities (z = i*y, wd = wr + i*wi, wx=-wr, wz=wr^2, t1=y-wi, t2=y+wi,
// d1=t1^2+wz, d2=t2^2+wz, g=y^2-wi^2):
//   dd   = d1*d2 = g^2 + 2*wz*y^2 + (wz^2 + 2*wz*wi^2)   [all terms >= 0]
//   d1+d2 = 2*y^2 + c3        d2-d1 = 4*y*wi
//   u1+u2 = 2*y*(g+wz)        u1-u2 = 2*wi*(g-wz)
__global__ __launch_bounds__(NTA, 8)
void cauchy_phase(const float* __restrict__ w_ri,
                  const float* __restrict__ p_ri,
                  const float* __restrict__ q_ri,
                  const float* __restrict__ B_ri,
                  const float* __restrict__ C_ri,
                  const float* __restrict__ log_dt,
                  float*       __restrict__ spec,   // (H, 4096) float2 rows (= d_out)
                  float2*      __restrict__ nyq)    // (H,) Nyquist bins (= d_ws)
{
    __shared__ PolePair s_pp[NP / 2];

    const int h     = blockIdx.y;
    const int chunk = blockIdx.x;      // 16 chunks of 256 bins
    const int tid   = threadIdx.x;
    const float dt  = expf(log_dt[h]);

    if (tid < NP) {
        const int n = tid;
        const int k = n >> 1, o = n & 1;
        const float2 w = ((const float2*)w_ri)[h * NP + n];
        const float2 p = ((const float2*)p_ri)[h * NP + n];
        const float2 q = ((const float2*)q_ri)[h * NP + n];
        const float2 B = ((const float2*)B_ri)[h * NP + n];
        const float2 C = ((const float2*)C_ri)[h * NP + n];
        const float wr = w.x * dt, wi = w.y * dt;
        const float wz = wr * wr, wisq = wi * wi;
        float* base = (float*)&s_pp[k];
        base[0 + o]  = -wisq;                       // nwisq
        base[2 + o]  = wz * wz + 2.f * wz * wisq;   // c1
        base[4 + o]  = 2.f * wz;                    // c2
        base[6 + o]  = 2.f * (wisq + wz);           // c3
        base[8 + o]  = wi;
        base[10 + o] = wz;
        base[12 + o] = -wz;                         // nwz
        base[14 + o] = 2.f * wi;                    // w2i
        base[16 + o] = -wr;                         // wx
        base[18 + o] = 0.f;                         // pad
        base[20 + o] = B.x * C.x + B.y * C.y;       // v00r
        base[22 + o] = B.y * C.x - B.x * C.y;       // v00i
        base[24 + o] = p.x * C.x + p.y * C.y;       // v01r
        base[26 + o] = p.y * C.x - p.x * C.y;       // v01i
        base[28 + o] = B.x * q.x + B.y * q.y;       // v10r
        base[30 + o] = B.y * q.x - B.x * q.y;       // v10i
        base[32 + o] = p.x * q.x + p.y * q.y;       // v11r
        base[34 + o] = p.y * q.x - p.x * q.y;       // v11i
    }
    __syncthreads();

    const int l = (chunk << 8) + tid;       // 0..4095
    // y = Im(z) = 2*tan(pi*l/L); rev = l/16384 (exact dyadic)
    const float rev = (float)l * 6.103515625e-5f;
    const float sn  = __builtin_amdgcn_sinf(rev);
    const float cn  = fmaxf(__builtin_amdgcn_cosf(rev), 4.3711388e-8f);
    const float y   = 2.0f * sn * __builtin_amdgcn_rcpf(cn);
    const float ysq = y * y;
    const v2f yA   = {ysq, ysq};                 // y^2
    const v2f yA2  = {2.f * ysq, 2.f * ysq};     // 2*y^2
    const v2f y4s  = {4.f * y, 4.f * y};         // 4*y
    const v2f ny2s = {-2.f * y, -2.f * y};       // -2*y

    v2f a0 = 0.f, a1 = 0.f, a2 = 0.f, a3 = 0.f;
    v2f a4 = 0.f, a5 = 0.f, a6 = 0.f, a7 = 0.f;
    #pragma unroll 2
    for (int k = 0; k < NP / 2; ++k) {
        const PolePair& pp = s_pp[k];
        const v2f nwisq = pp.nwisq, c1 = pp.c1, c2 = pp.c2, c3 = pp.c3;
        const v2f wi2 = pp.wi, wz2 = pp.wz, nwz2 = pp.nwz, w2i = pp.w2i;
        const v2f wx2 = pp.wx;
        const v2f v00r2 = pp.v00r, v00i2 = pp.v00i;
        const v2f v01r2 = pp.v01r, v01i2 = pp.v01i;
        const v2f v10r2 = pp.v10r, v10i2 = pp.v10i;
        const v2f v11r2 = pp.v11r, v11i2 = pp.v11i;

        v2f g, inner, dd;
        asm("v_pk_add_f32 %0, %3, %4\n\t"        // g = y^2 + (-wi^2)
            "v_pk_fma_f32 %1, %5, %3, %6\n\t"    // inner = c2*y^2 + c1
            "v_pk_fma_f32 %2, %0, %0, %1"        // dd = g*g + inner
            : "=&v"(g), "=&v"(inner), "=&v"(dd)
            : "v"(yA), "v"(nwisq), "v"(c2), "v"(c1));

        const v2f ir = {__builtin_amdgcn_rcpf(dd.x), __builtin_amdgcn_rcpf(dd.y)};

        v2f Sr, Di, SiN, Dr, scr;
        asm("v_pk_add_f32 %0, %5, %6\n\t"        // SI  = 2y^2 + c3      (d1+d2)
            "v_pk_mul_f32 %1, %7, %8\n\t"        // DI  = 4y * wi        (d2-d1)
            "v_pk_add_f32 %2, %9, %10\n\t"       // h1  = g + wz
            "v_pk_add_f32 %3, %9, %11\n\t"       // h2  = g + (-wz)
            "v_pk_mul_f32 %2, %12, %2\n\t"       // SPn = -2y * h1       (-(u1+u2))
            "v_pk_mul_f32 %3, %13, %3\n\t"       // SM  = 2wi * h2       ((u1-u2))
            "v_pk_mul_f32 %4, %14, %15\n\t"      // irx = wx * ir
            "v_pk_mul_f32 %0, %0, %4\n\t"        // Sr  = SI * irx
            "v_pk_mul_f32 %1, %1, %4\n\t"        // Di  = DI * irx
            "v_pk_mul_f32 %3, %3, %15\n\t"       // Dr  = SM * ir
            "v_pk_mul_f32 %2, %2, %15"           // SiN = SPn * ir       (= Si)
            : "=&v"(Sr), "=&v"(Di), "=&v"(SiN), "=&v"(Dr), "=&v"(scr)
            : "v"(yA2), "v"(c3), "v"(y4s), "v"(wi2), "v"(g), "v"(wz2),
              "v"(nwz2), "v"(ny2s), "v"(w2i), "v"(wx2), "v"(ir));

        asm("v_pk_fma_f32 %0, %12, %8, %0\n\t"   // a0 += v00r*Sr
            "v_pk_fma_f32 %0, %13, %10, %0\n\t"  // a0 += v00i*Dr
            "v_pk_fma_f32 %1, %12, %9, %1\n\t"   // a1 += v00r*SiN
            "v_pk_fma_f32 %1, %13, %11, %1\n\t"  // a1 += v00i*Di
            "v_pk_fma_f32 %2, %14, %8, %2\n\t"
            "v_pk_fma_f32 %2, %15, %10, %2\n\t"
            "v_pk_fma_f32 %3, %14, %9, %3\n\t"
            "v_pk_fma_f32 %3, %15, %11, %3\n\t"
            "v_pk_fma_f32 %4, %16, %8, %4\n\t"
            "v_pk_fma_f32 %4, %17, %10, %4\n\t"
            "v_pk_fma_f32 %5, %16, %9, %5\n\t"
            "v_pk_fma_f32 %5, %17, %11, %5\n\t"
            "v_pk_fma_f32 %6, %18, %8, %6\n\t"
            "v_pk_fma_f32 %6, %19, %10, %6\n\t"
            "v_pk_fma_f32 %7, %18, %9, %7\n\t"
            "v_pk_fma_f32 %7, %19, %11, %7"
            : "+v"(a0), "+v"(a1), "+v"(a2), "+v"(a3),
              "+v"(a4), "+v"(a5), "+v"(a6), "+v"(a7)
            : "v"(Sr), "v"(SiN), "v"(Dr), "v"(Di),
              "v"(v00r2), "v"(v00i2), "v"(v01r2), "v"(v01i2),
              "v"(v10r2), "v"(v10i2), "v"(v11r2), "v"(v11i2));
    }

    // horizontal add over the pole-pair halves, then Woodbury
    {
        const float a00r = (a0.x + a0.y) * dt, a00i = (a1.x + a1.y) * dt;
        const float a01r = (a2.x + a2.y) * dt, a01i = (a3.x + a3.y) * dt;
        const float a10r = (a4.x + a4.y) * dt, a10i = (a5.x + a5.y) * dt;
        const float a11r = (a6.x + a6.y) * dt, a11i = (a7.x + a7.y) * dt;
        const float numr = a01r * a10r - a01i * a10i;
        const float numi = a01r * a10i + a01i * a10r;
        const float dwr = 1.f + a11r, dwi = a11i;
        const float idw = __builtin_amdgcn_rcpf(dwr * dwr + dwi * dwi);
        const float qr = (numr * dwr + numi * dwi) * idw;
        const float qi = (numi * dwr - numr * dwi) * idw;
        const float kfr = a00r - qr, kfi = a00i - qi;
        const float fi  = 0.5f * y;        // 2/(1+nodes) = 1 + i*tan(pi*l/L)
        float2* grow = (float2*)(spec + (size_t)h * LL);
        grow[l] = make_float2(kfr - kfi * fi, kfi + kfr * fi);
    }

    // ---- Nyquist bin l=4096: one pole per lane of wave 0 of chunk 15 ----
    if (chunk == 15 && tid < 64) {
        const int n = tid;
        const int k = n >> 1, o = n & 1;
        const float* base = (const float*)&s_pp[k];
        const float wi = base[8 + o];
        const float wz = base[10 + o];
        const float wx = base[16 + o];
        const float v00r = base[20 + o], v00i = base[22 + o];
        const float v01r = base[24 + o], v01i = base[26 + o];
        const float v10r = base[28 + o], v10i = base[30 + o];
        const float v11r = base[32 + o], v11i = base[34 + o];
        // rev = 0.25 -> cos = 0 exactly; clamp reproduces reference's f32 z ~ 4.58e7
        const float y4 = 2.0f * __builtin_amdgcn_rcpf(4.3711388e-8f);
        const float t1 = y4 - wi, t2 = y4 + wi;
        const float i1 = __builtin_amdgcn_rcpf(fmaf(t1, t1, wz));
        const float i2 = __builtin_amdgcn_rcpf(fmaf(t2, t2, wz));
        const float u1 = t1 * i1, u2 = t2 * i2;
        const float Sr = wx * (i1 + i2);
        const float Si = -(u1 + u2);
        const float Dr = u1 - u2;
        const float Di = wx * (i1 - i2);
        float e0 = v00r * Sr + v00i * Dr, e1 = v00r * Si + v00i * Di;
        float e2 = v01r * Sr + v01i * Dr, e3 = v01r * Si + v01i * Di;
        float e4 = v10r * Sr + v10i * Dr, e5 = v10r * Si + v10i * Di;
        float e6 = v11r * Sr + v11i * Dr, e7 = v11r * Si + v11i * Di;
        #pragma unroll
        for (int m = 1; m < 64; m <<= 1) {
            e0 += __shfl_xor(e0, m);  e1 += __shfl_xor(e1, m);
            e2 += __shfl_xor(e2, m);  e3 += __shfl_xor(e3, m);
            e4 += __shfl_xor(e4, m);  e5 += __shfl_xor(e5, m);
            e6 += __shfl_xor(e6, m);  e7 += __shfl_xor(e7, m);
        }
        if (tid == 0) {
            const float a00r = e0 * dt, a00i = e1 * dt;
            const float a01r = e2 * dt, a01i = e3 * dt;
            const float a10r = e4 * dt, a10i = e5 * dt;
            const float a11r = e6 * dt, a11i = e7 * dt;
            const float numr = a01r * a10r - a01i * a10i;
            const float numi = a01r * a10i + a01i * a10r;
            const float dwr = 1.f + a11r, dwi = a11i;
            const float idw = __builtin_amdgcn_rcpf(dwr * dwr + dwi * dwi);
            const float qr = (numr * dwr + numi * dwi) * idw;
            const float qi = (numi * dwr - numr * dwi) * idw;
            const float kfr = a00r - qr, kfi = a00i - qi;
            const float fi  = 0.5f * y4;
            nyq[h] = make_float2(kfr - kfi * fi, kfi + kfr * fi);
        }
    }
}

// ---------------- Kernel B: pack + radix-4 Stockham iFFT + store -------------
__global__ __launch_bounds__(NTB)
void ifft_phase(float* __restrict__ io, const float2* __restrict__ nyq)
{
    __shared__ float2 sA[NHALF];
    __shared__ float2 sB[NHALF];

    const int h   = blockIdx.x;
    const int tid = threadIdx.x;
    float2* grow = (float2*)(io + (size_t)h * LL);

    // pack irfft(L) into complex iFFT(L/2), natural order:
    // Z[k] = (1/L)[(G[k]+conj(G[N-k])) + i*e^{+2pi i k/L}(G[k]-conj(G[N-k]))]
    #pragma unroll
    for (int ki = 0; ki < 4; ++ki) {
        const int k = tid + NTB * ki;
        const float2 Gk = grow[k];
        const float2 Gn = (k == 0) ? nyq[h] : grow[NHALF - k];
        const float Ar = Gk.x + Gn.x, Ai = Gk.y - Gn.y;
        const float Br = Gk.x - Gn.x, Bi = Gk.y + Gn.y;
        const float rev = (float)k * 1.220703125e-4f;   // k/8192
        const float cw = __builtin_amdgcn_cosf(rev);
        const float sw = __builtin_amdgcn_sinf(rev);
        const float sc = 1.0f / (float)LL;
        sA[k] = make_float2((Ar - cw * Bi - sw * Br) * sc,
                            (Ai + cw * Br - sw * Bi) * sc);
    }
    __syncthreads();

    // 6 radix-4 Stockham stages (inverse FFT, e^{+i} twiddles), ping-pong sA<->sB
    float2* pin  = sA;
    float2* pout = sB;
    #pragma unroll
    for (int s = 0; s < 6; ++s) {
        const int ls2 = 2 * s;
        const int Ls  = 1 << ls2;
        const int j   = tid;
        const int k   = j & (Ls - 1);
        const int tb  = k << (10 - ls2);
        const float fr = (float)tb * 2.44140625e-4f;    // tb/4096 revolutions
        const float c1 = __builtin_amdgcn_cosf(fr);
        const float s1 = __builtin_amdgcn_sinf(fr);
        const float c2 = __builtin_amdgcn_cosf(2.0f * fr);
        const float s2 = __builtin_amdgcn_sinf(2.0f * fr);
        const float c3 = __builtin_amdgcn_cosf(3.0f * fr);
        const float s3 = __builtin_amdgcn_sinf(3.0f * fr);
        float2 u0 = pin[j];
        float2 u1 = pin[j + 1024];
        float2 u2 = pin[j + 2048];
        float2 u3 = pin[j + 3072];
        float a, b;
        a = u1.x * c1 - u1.y * s1;  b = u1.x * s1 + u1.y * c1;  u1 = make_float2(a, b);
        a = u2.x * c2 - u2.y * s2;  b = u2.x * s2 + u2.y * c2;  u2 = make_float2(a, b);
        a = u3.x * c3 - u3.y * s3;  b = u3.x * s3 + u3.y * c3;  u3 = make_float2(a, b);
        const float t0r = u0.x + u2.x, t0i = u0.y + u2.y;
        const float t1r = u0.x - u2.x, t1i = u0.y - u2.y;
        const float t2r = u1.x + u3.x, t2i = u1.y + u3.y;
        const float t3r = u3.y - u1.y, t3i = u1.x - u3.x;   // i*(u1-u3)
        const int ob = ((j - k) << 2) + k;
        pout[ob]          = make_float2(t0r + t2r, t0i + t2i);
        pout[ob + Ls]     = make_float2(t1r + t3r, t1i + t3i);
        pout[ob + 2 * Ls] = make_float2(t0r - t2r, t0i - t2i);
        pout[ob + 3 * Ls] = make_float2(t1r - t3r, t1i - t3i);
        float2* tmp = pin; pin = pout; pout = tmp;
        __syncthreads();
    }

    // final data lands in sA; x[2j]=Re, x[2j+1]=Im -> coalesced float2 store
    #pragma unroll
    for (int ji = 0; ji < 4; ++ji) {
        const int j = tid + NTB * ji;
        grow[j] = sA[j];
    }
}

extern "C" void kernel_launch(void* const* d_in, const int* in_sizes, int n_in,
                              void* d_out, int out_size, void* d_ws, size_t ws_size,
                              hipStream_t stream) {
    const float* w   = (const float*)d_in[0];
    const float* p   = (const float*)d_in[1];
    const float* q   = (const float*)d_in[2];
    const float* B   = (const float*)d_in[3];
    const float* C   = (const float*)d_in[4];
    const float* ldt = (const float*)d_in[5];
    float*  spec = (float*)d_out;          // spectrum staged in-place in d_out
    float2* nyq  = (float2*)d_ws;          // 256 * 8 B Nyquist bins

    dim3 gridA(16, NUM_H);
    cauchy_phase<<<gridA, NTA, 0, stream>>>(w, p, q, B, C, ldt, spec, nyq);
    ifft_phase<<<NUM_H, NTB, 0, stream>>>(spec, nyq);
}

// Round 13
// 52.836 us; speedup vs baseline: 1.1463x; 1.0912x over previous
//
#include <hip/hip_runtime.h>
#include <math.h>

#define NUM_H 256
#define NP    64        // poles per h
#define LL    8192      // sequence length
#define NHALF 4096      // LL/2 (complex FFT size)
#define NTA   256       // threads, Cauchy kernel
#define NTB   1024      // threads, FFT kernel

typedef float v2f __attribute__((ext_vector_type(2)));

// v_sin_f32 / v_cos_f32 take input in REVOLUTIONS (D = sin(S0 * 2pi)).

// Per pole-pair constants; every field is a native v2f pair (even-aligned
// VGPR pair = direct VOP3P asm operand). Same layout as rounds 9/12.
struct PolePair {
    v2f nwisq, c1;     // floats 0-3   nwisq = -wi^2 ; c1 = wz^2 + 2*wz*wi^2
    v2f c2,    c3;     // 4-7          c2 = 2*wz     ; c3 = 2*(wi^2+wz)
    v2f wi,    wz;     // 8-11
    v2f nwz,   w2i;    // 12-15        nwz = -wz     ; w2i = 2*wi
    v2f wx,    pad;    // 16-19        wx = -wr
    v2f v00r,  v00i;   // 20-23        B*conj(C)
    v2f v01r,  v01i;   // 24-27        p*conj(C)
    v2f v10r,  v10i;   // 28-31        B*conj(q)
    v2f v11r,  v11i;   // 32-35        p*conj(q)
};

// ---------------- Kernel A: Cauchy sum + Woodbury -> spectrum ----------------
// Each thread owns TWO bins (l, l+2048); inner loop processes a pole PAIR per
// iteration with the round-12-proven modifier-free VOP3P asm, duplicated per
// bin; the 17 constant v2f loads are shared across both bins. No min-waves
// launch bound: unconstrained RA (round 8's timeout is attributed to RA under
// a 128-VGPR cap with ~100 VGPRs of tied 64-bit asm operands).
__global__ __launch_bounds__(NTA)
void cauchy_phase(const float* __restrict__ w_ri,
                  const float* __restrict__ p_ri,
                  const float* __restrict__ q_ri,
                  const float* __restrict__ B_ri,
                  const float* __restrict__ C_ri,
                  const float* __restrict__ log_dt,
                  float*       __restrict__ spec,   // (H, 4096) float2 rows (= d_out)
                  float2*      __restrict__ nyq)    // (H,) Nyquist bins (= d_ws)
{
    __shared__ PolePair s_pp[NP / 2];

    const int h     = blockIdx.y;
    const int chunk = blockIdx.x;      // 8 chunks of 256 low bins
    const int tid   = threadIdx.x;
    const float dt  = expf(log_dt[h]);

    if (tid < NP) {
        const int n = tid;
        const int k = n >> 1, o = n & 1;
        const float2 w = ((const float2*)w_ri)[h * NP + n];
        const float2 p = ((const float2*)p_ri)[h * NP + n];
        const float2 q = ((const float2*)q_ri)[h * NP + n];
        const float2 B = ((const float2*)B_ri)[h * NP + n];
        const float2 C = ((const float2*)C_ri)[h * NP + n];
        const float wr = w.x * dt, wi = w.y * dt;
        const float wz = wr * wr, wisq = wi * wi;
        float* base = (float*)&s_pp[k];
        base[0 + o]  = -wisq;                       // nwisq
        base[2 + o]  = wz * wz + 2.f * wz * wisq;   // c1
        base[4 + o]  = 2.f * wz;                    // c2
        base[6 + o]  = 2.f * (wisq + wz);           // c3
        base[8 + o]  = wi;
        base[10 + o] = wz;
        base[12 + o] = -wz;                         // nwz
        base[14 + o] = 2.f * wi;                    // w2i
        base[16 + o] = -wr;                         // wx
        base[18 + o] = 0.f;                         // pad
        base[20 + o] = B.x * C.x + B.y * C.y;       // v00r
        base[22 + o] = B.y * C.x - B.x * C.y;       // v00i
        base[24 + o] = p.x * C.x + p.y * C.y;       // v01r
        base[26 + o] = p.y * C.x - p.x * C.y;       // v01i
        base[28 + o] = B.x * q.x + B.y * q.y;       // v10r
        base[30 + o] = B.y * q.x - B.x * q.y;       // v10i
        base[32 + o] = p.x * q.x + p.y * q.y;       // v11r
        base[34 + o] = p.y * q.x - p.x * q.y;       // v11i
    }
    __syncthreads();

    const int lA = (chunk << 8) + tid;       // 0..2047
    const int lB = lA + 2048;                // 2048..4095
    // y = Im(z) = 2*tan(pi*l/L); rev = l/16384 (exact dyadic)
    float yS[2];
    #pragma unroll
    for (int b = 0; b < 2; ++b) {
        const int l = lA + (b << 11);
        const float rev = (float)l * 6.103515625e-5f;
        const float sn  = __builtin_amdgcn_sinf(rev);
        const float cn  = fmaxf(__builtin_amdgcn_cosf(rev), 4.3711388e-8f);
        yS[b] = 2.0f * sn * __builtin_amdgcn_rcpf(cn);
    }
    const float yAv = yS[0], yBv = yS[1];
    const v2f yA_A   = {yAv * yAv, yAv * yAv};
    const v2f yA2_A  = {2.f * yAv * yAv, 2.f * yAv * yAv};
    const v2f y4s_A  = {4.f * yAv, 4.f * yAv};
    const v2f ny2s_A = {-2.f * yAv, -2.f * yAv};
    const v2f yA_B   = {yBv * yBv, yBv * yBv};
    const v2f yA2_B  = {2.f * yBv * yBv, 2.f * yBv * yBv};
    const v2f y4s_B  = {4.f * yBv, 4.f * yBv};
    const v2f ny2s_B = {-2.f * yBv, -2.f * yBv};

    v2f a0 = 0.f, a1 = 0.f, a2 = 0.f, a3 = 0.f;
    v2f a4 = 0.f, a5 = 0.f, a6 = 0.f, a7 = 0.f;
    v2f b0 = 0.f, b1 = 0.f, b2 = 0.f, b3 = 0.f;
    v2f b4 = 0.f, b5 = 0.f, b6 = 0.f, b7 = 0.f;
    #pragma unroll 1
    for (int k = 0; k < NP / 2; ++k) {
        const PolePair& pp = s_pp[k];
        const v2f nwisq = pp.nwisq, c1 = pp.c1, c2 = pp.c2, c3 = pp.c3;
        const v2f wi2 = pp.wi, wz2 = pp.wz, nwz2 = pp.nwz, w2i = pp.w2i;
        const v2f wx2 = pp.wx;
        const v2f v00r2 = pp.v00r, v00i2 = pp.v00i;
        const v2f v01r2 = pp.v01r, v01i2 = pp.v01i;
        const v2f v10r2 = pp.v10r, v10i2 = pp.v10i;
        const v2f v11r2 = pp.v11r, v11i2 = pp.v11i;

        // ---- bin A ----
        v2f gA, inA, ddA;
        asm("v_pk_add_f32 %0, %3, %4\n\t"        // g = y^2 + (-wi^2)
            "v_pk_fma_f32 %1, %5, %3, %6\n\t"    // inner = c2*y^2 + c1
            "v_pk_fma_f32 %2, %0, %0, %1"        // dd = g*g + inner
            : "=&v"(gA), "=&v"(inA), "=&v"(ddA)
            : "v"(yA_A), "v"(nwisq), "v"(c2), "v"(c1));
        const v2f irA = {__builtin_amdgcn_rcpf(ddA.x), __builtin_amdgcn_rcpf(ddA.y)};
        v2f SrA, DiA, SiNA, DrA, scrA;
        asm("v_pk_add_f32 %0, %5, %6\n\t"        // SI  = 2y^2 + c3      (d1+d2)
            "v_pk_mul_f32 %1, %7, %8\n\t"        // DI  = 4y * wi        (d2-d1)
            "v_pk_add_f32 %2, %9, %10\n\t"       // h1  = g + wz
            "v_pk_add_f32 %3, %9, %11\n\t"       // h2  = g + (-wz)
            "v_pk_mul_f32 %2, %12, %2\n\t"       // SPn = -2y * h1
            "v_pk_mul_f32 %3, %13, %3\n\t"       // SM  = 2wi * h2
            "v_pk_mul_f32 %4, %14, %15\n\t"      // irx = wx * ir
            "v_pk_mul_f32 %0, %0, %4\n\t"        // Sr  = SI * irx
            "v_pk_mul_f32 %1, %1, %4\n\t"        // Di  = DI * irx
            "v_pk_mul_f32 %3, %3, %15\n\t"       // Dr  = SM * ir
            "v_pk_mul_f32 %2, %2, %15"           // SiN = SPn * ir
            : "=&v"(SrA), "=&v"(DiA), "=&v"(SiNA), "=&v"(DrA), "=&v"(scrA)
            : "v"(yA2_A), "v"(c3), "v"(y4s_A), "v"(wi2), "v"(gA), "v"(wz2),
              "v"(nwz2), "v"(ny2s_A), "v"(w2i), "v"(wx2), "v"(irA));

        // ---- bin B ----
        v2f gB, inB, ddB;
        asm("v_pk_add_f32 %0, %3, %4\n\t"
            "v_pk_fma_f32 %1, %5, %3, %6\n\t"
            "v_pk_fma_f32 %2, %0, %0, %1"
            : "=&v"(gB), "=&v"(inB), "=&v"(ddB)
            : "v"(yA_B), "v"(nwisq), "v"(c2), "v"(c1));
        const v2f irB = {__builtin_amdgcn_rcpf(ddB.x), __builtin_amdgcn_rcpf(ddB.y)};
        v2f SrB, DiB, SiNB, DrB, scrB;
        asm("v_pk_add_f32 %0, %5, %6\n\t"
            "v_pk_mul_f32 %1, %7, %8\n\t"
            "v_pk_add_f32 %2, %9, %10\n\t"
            "v_pk_add_f32 %3, %9, %11\n\t"
            "v_pk_mul_f32 %2, %12, %2\n\t"
            "v_pk_mul_f32 %3, %13, %3\n\t"
            "v_pk_mul_f32 %4, %14, %15\n\t"
            "v_pk_mul_f32 %0, %0, %4\n\t"
            "v_pk_mul_f32 %1, %1, %4\n\t"
            "v_pk_mul_f32 %3, %3, %15\n\t"
            "v_pk_mul_f32 %2, %2, %15"
            : "=&v"(SrB), "=&v"(DiB), "=&v"(SiNB), "=&v"(DrB), "=&v"(scrB)
            : "v"(yA2_B), "v"(c3), "v"(y4s_B), "v"(wi2), "v"(gB), "v"(wz2),
              "v"(nwz2), "v"(ny2s_B), "v"(w2i), "v"(wx2), "v"(irB));

        // ---- accumulate bin A ----
        asm("v_pk_fma_f32 %0, %12, %8, %0\n\t"
            "v_pk_fma_f32 %0, %13, %10, %0\n\t"
            "v_pk_fma_f32 %1, %12, %9, %1\n\t"
            "v_pk_fma_f32 %1, %13, %11, %1\n\t"
            "v_pk_fma_f32 %2, %14, %8, %2\n\t"
            "v_pk_fma_f32 %2, %15, %10, %2\n\t"
            "v_pk_fma_f32 %3, %14, %9, %3\n\t"
            "v_pk_fma_f32 %3, %15, %11, %3\n\t"
            "v_pk_fma_f32 %4, %16, %8, %4\n\t"
            "v_pk_fma_f32 %4, %17, %10, %4\n\t"
            "v_pk_fma_f32 %5, %16, %9, %5\n\t"
            "v_pk_fma_f32 %5, %17, %11, %5\n\t"
            "v_pk_fma_f32 %6, %18, %8, %6\n\t"
            "v_pk_fma_f32 %6, %19, %10, %6\n\t"
            "v_pk_fma_f32 %7, %18, %9, %7\n\t"
            "v_pk_fma_f32 %7, %19, %11, %7"
            : "+v"(a0), "+v"(a1), "+v"(a2), "+v"(a3),
              "+v"(a4), "+v"(a5), "+v"(a6), "+v"(a7)
            : "v"(SrA), "v"(SiNA), "v"(DrA), "v"(DiA),
              "v"(v00r2), "v"(v00i2), "v"(v01r2), "v"(v01i2),
              "v"(v10r2), "v"(v10i2), "v"(v11r2), "v"(v11i2));

        // ---- accumulate bin B ----
        asm("v_pk_fma_f32 %0, %12, %8, %0\n\t"
            "v_pk_fma_f32 %0, %13, %10, %0\n\t"
            "v_pk_fma_f32 %1, %12, %9, %1\n\t"
            "v_pk_fma_f32 %1, %13, %11, %1\n\t"
            "v_pk_fma_f32 %2, %14, %8, %2\n\t"
            "v_pk_fma_f32 %2, %15, %10, %2\n\t"
            "v_pk_fma_f32 %3, %14, %9, %3\n\t"
            "v_pk_fma_f32 %3, %15, %11, %3\n\t"
            "v_pk_fma_f32 %4, %16, %8, %4\n\t"
            "v_pk_fma_f32 %4, %17, %10, %4\n\t"
            "v_pk_fma_f32 %5, %16, %9, %5\n\t"
            "v_pk_fma_f32 %5, %17, %11, %5\n\t"
            "v_pk_fma_f32 %6, %18, %8, %6\n\t"
            "v_pk_fma_f32 %6, %19, %10, %6\n\t"
            "v_pk_fma_f32 %7, %18, %9, %7\n\t"
            "v_pk_fma_f32 %7, %19, %11, %7"
            : "+v"(b0), "+v"(b1), "+v"(b2), "+v"(b3),
              "+v"(b4), "+v"(b5), "+v"(b6), "+v"(b7)
            : "v"(SrB), "v"(SiNB), "v"(DrB), "v"(DiB),
              "v"(v00r2), "v"(v00i2), "v"(v01r2), "v"(v01i2),
              "v"(v10r2), "v"(v10i2), "v"(v11r2), "v"(v11i2));
    }

    // horizontal add over the pole-pair halves, then Woodbury (per bin)
    float2* grow = (float2*)(spec + (size_t)h * LL);
    {
        const float a00r = (a0.x + a0.y) * dt, a00i = (a1.x + a1.y) * dt;
        const float a01r = (a2.x + a2.y) * dt, a01i = (a3.x + a3.y) * dt;
        const float a10r = (a4.x + a4.y) * dt, a10i = (a5.x + a5.y) * dt;
        const float a11r = (a6.x + a6.y) * dt, a11i = (a7.x + a7.y) * dt;
        const float numr = a01r * a10r - a01i * a10i;
        const float numi = a01r * a10i + a01i * a10r;
        const float dwr = 1.f + a11r, dwi = a11i;
        const float idw = __builtin_amdgcn_rcpf(dwr * dwr + dwi * dwi);
        const float qr = (numr * dwr + numi * dwi) * idw;
        const float qi = (numi * dwr - numr * dwi) * idw;
        const float kfr = a00r - qr, kfi = a00i - qi;
        const float fi  = 0.5f * yAv;      // 2/(1+nodes) = 1 + i*tan(pi*l/L)
        grow[lA] = make_float2(kfr - kfi * fi, kfi + kfr * fi);
    }
    {
        const float a00r = (b0.x + b0.y) * dt, a00i = (b1.x + b1.y) * dt;
        const float a01r = (b2.x + b2.y) * dt, a01i = (b3.x + b3.y) * dt;
        const float a10r = (b4.x + b4.y) * dt, a10i = (b5.x + b5.y) * dt;
        const float a11r = (b6.x + b6.y) * dt, a11i = (b7.x + b7.y) * dt;
        const float numr = a01r * a10r - a01i * a10i;
        const float numi = a01r * a10i + a01i * a10r;
        const float dwr = 1.f + a11r, dwi = a11i;
        const float idw = __builtin_amdgcn_rcpf(dwr * dwr + dwi * dwi);
        const float qr = (numr * dwr + numi * dwi) * idw;
        const float qi = (numi * dwr - numr * dwi) * idw;
        const float kfr = a00r - qr, kfi = a00i - qi;
        const float fi  = 0.5f * yBv;
        grow[lB] = make_float2(kfr - kfi * fi, kfi + kfr * fi);
    }

    // ---- Nyquist bin l=4096: one pole per lane of wave 0 of chunk 7 ----
    if (chunk == 7 && tid < 64) {
        const int n = tid;
        const int k = n >> 1, o = n & 1;
        const float* base = (const float*)&s_pp[k];
        const float wi = base[8 + o];
        const float wz = base[10 + o];
        const float wx = base[16 + o];
        const float v00r = base[20 + o], v00i = base[22 + o];
        const float v01r = base[24 + o], v01i = base[26 + o];
        const float v10r = base[28 + o], v10i = base[30 + o];
        const float v11r = base[32 + o], v11i = base[34 + o];
        // rev = 0.25 -> cos = 0 exactly; clamp reproduces reference's f32 z ~ 4.58e7
        const float y4 = 2.0f * __builtin_amdgcn_rcpf(4.3711388e-8f);
        const float t1 = y4 - wi, t2 = y4 + wi;
        const float i1 = __builtin_amdgcn_rcpf(fmaf(t1, t1, wz));
        const float i2 = __builtin_amdgcn_rcpf(fmaf(t2, t2, wz));
        const float u1 = t1 * i1, u2 = t2 * i2;
        const float Sr = wx * (i1 + i2);
        const float Si = -(u1 + u2);
        const float Dr = u1 - u2;
        const float Di = wx * (i1 - i2);
        float e0 = v00r * Sr + v00i * Dr, e1 = v00r * Si + v00i * Di;
        float e2 = v01r * Sr + v01i * Dr, e3 = v01r * Si + v01i * Di;
        float e4 = v10r * Sr + v10i * Dr, e5 = v10r * Si + v10i * Di;
        float e6 = v11r * Sr + v11i * Dr, e7 = v11r * Si + v11i * Di;
        #pragma unroll
        for (int m = 1; m < 64; m <<= 1) {
            e0 += __shfl_xor(e0, m);  e1 += __shfl_xor(e1, m);
            e2 += __shfl_xor(e2, m);  e3 += __shfl_xor(e3, m);
            e4 += __shfl_xor(e4, m);  e5 += __shfl_xor(e5, m);
            e6 += __shfl_xor(e6, m);  e7 += __shfl_xor(e7, m);
        }
        if (tid == 0) {
            const float a00r = e0 * dt, a00i = e1 * dt;
            const float a01r = e2 * dt, a01i = e3 * dt;
            const float a10r = e4 * dt, a10i = e5 * dt;
            const float a11r = e6 * dt, a11i = e7 * dt;
            const float numr = a01r * a10r - a01i * a10i;
            const float numi = a01r * a10i + a01i * a10r;
            const float dwr = 1.f + a11r, dwi = a11i;
            const float idw = __builtin_amdgcn_rcpf(dwr * dwr + dwi * dwi);
            const float qr = (numr * dwr + numi * dwi) * idw;
            const float qi = (numi * dwr - numr * dwi) * idw;
            const float kfr = a00r - qr, kfi = a00i - qi;
            const float fi  = 0.5f * y4;
            nyq[h] = make_float2(kfr - kfi * fi, kfi + kfr * fi);
        }
    }
}

// ---------------- Kernel B: pack + radix-4 Stockham iFFT + store -------------
__global__ __launch_bounds__(NTB)
void ifft_phase(float* __restrict__ io, const float2* __restrict__ nyq)
{
    __shared__ float2 sA[NHALF];
    __shared__ float2 sB[NHALF];

    const int h   = blockIdx.x;
    const int tid = threadIdx.x;
    float2* grow = (float2*)(io + (size_t)h * LL);

    // pack irfft(L) into complex iFFT(L/2), natural order:
    // Z[k] = (1/L)[(G[k]+conj(G[N-k])) + i*e^{+2pi i k/L}(G[k]-conj(G[N-k]))]
    #pragma unroll
    for (int ki = 0; ki < 4; ++ki) {
        const int k = tid + NTB * ki;
        const float2 Gk = grow[k];
        const float2 Gn = (k == 0) ? nyq[h] : grow[NHALF - k];
        const float Ar = Gk.x + Gn.x, Ai = Gk.y - Gn.y;
        const float Br = Gk.x - Gn.x, Bi = Gk.y + Gn.y;
        const float rev = (float)k * 1.220703125e-4f;   // k/8192
        const float cw = __builtin_amdgcn_cosf(rev);
        const float sw = __builtin_amdgcn_sinf(rev);
        const float sc = 1.0f / (float)LL;
        sA[k] = make_float2((Ar - cw * Bi - sw * Br) * sc,
                            (Ai + cw * Br - sw * Bi) * sc);
    }
    __syncthreads();

    // 6 radix-4 Stockham stages (inverse FFT, e^{+i} twiddles), ping-pong sA<->sB
    float2* pin  = sA;
    float2* pout = sB;
    #pragma unroll
    for (int s = 0; s < 6; ++s) {
        const int ls2 = 2 * s;
        const int Ls  = 1 << ls2;
        const int j   = tid;
        const int k   = j & (Ls - 1);
        const int tb  = k << (10 - ls2);
        const float fr = (float)tb * 2.44140625e-4f;    // tb/4096 revolutions
        const float c1 = __builtin_amdgcn_cosf(fr);
        const float s1 = __builtin_amdgcn_sinf(fr);
        const float c2 = __builtin_amdgcn_cosf(2.0f * fr);
        const float s2 = __builtin_amdgcn_sinf(2.0f * fr);
        const float c3 = __builtin_amdgcn_cosf(3.0f * fr);
        const float s3 = __builtin_amdgcn_sinf(3.0f * fr);
        float2 u0 = pin[j];
        float2 u1 = pin[j + 1024];
        float2 u2 = pin[j + 2048];
        float2 u3 = pin[j + 3072];
        float a, b;
        a = u1.x * c1 - u1.y * s1;  b = u1.x * s1 + u1.y * c1;  u1 = make_float2(a, b);
        a = u2.x * c2 - u2.y * s2;  b = u2.x * s2 + u2.y * c2;  u2 = make_float2(a, b);
        a = u3.x * c3 - u3.y * s3;  b = u3.x * s3 + u3.y * c3;  u3 = make_float2(a, b);
        const float t0r = u0.x + u2.x, t0i = u0.y + u2.y;
        const float t1r = u0.x - u2.x, t1i = u0.y - u2.y;
        const float t2r = u1.x + u3.x, t2i = u1.y + u3.y;
        const float t3r = u3.y - u1.y, t3i = u1.x - u3.x;   // i*(u1-u3)
        const int ob = ((j - k) << 2) + k;
        pout[ob]          = make_float2(t0r + t2r, t0i + t2i);
        pout[ob + Ls]     = make_float2(t1r + t3r, t1i + t3i);
        pout[ob + 2 * Ls] = make_float2(t0r - t2r, t0i - t2i);
        pout[ob + 3 * Ls] = make_float2(t1r - t3r, t1i - t3i);
        float2* tmp = pin; pin = pout; pout = tmp;
        __syncthreads();
    }

    // final data lands in sA; x[2j]=Re, x[2j+1]=Im -> coalesced float2 store
    #pragma unroll
    for (int ji = 0; ji < 4; ++ji) {
        const int j = tid + NTB * ji;
        grow[j] = sA[j];
    }
}

extern "C" void kernel_launch(void* const* d_in, const int* in_sizes, int n_in,
                              void* d_out, int out_size, void* d_ws, size_t ws_size,
                              hipStream_t stream) {
    const float* w   = (const float*)d_in[0];
    const float* p   = (const float*)d_in[1];
    const float* q   = (const float*)d_in[2];
    const float* B   = (const float*)d_in[3];
    const float* C   = (const float*)d_in[4];
    const float* ldt = (const float*)d_in[5];
    float*  spec = (float*)d_out;          // spectrum staged in-place in d_out
    float2* nyq  = (float2*)d_ws;          // 256 * 8 B Nyquist bins

    dim3 gridA(8, NUM_H);
    cauchy_phase<<<gridA, NTA, 0, stream>>>(w, p, q, B, C, ldt, spec, nyq);
    ifft_phase<<<NUM_H, NTB, 0, stream>>>(spec, nyq);
}